// Round 5
// baseline (473.067 us; speedup 1.0000x reference)
//
#include <hip/hip_runtime.h>
#include <math.h>

#define BPIX 64      // pixels per block (one row segment: 320 = 5*64)
#define HW   76800   // H*W
#define W_   320
#define H_   240
#define ENC_W 160
#define ENC_H 120
#define CENC 64
#define CSEG 21
#define NCH  85      // CENC + CSEG
#define ROW  90      // floats per output row: 2 + 85 + 3
#define PIXF 630     // 7 * 90 floats per pixel
#define TPLS 94      // template row stride (even -> float2 aligned)
#define NT2  2880    // BPIX * 45 template float2 positions per block

// ---------------------------------------------------------------------------
// Per-batch constants: K_inv (16), c2f translation -fmin/VOXEL (3), pad_off (3)
// ---------------------------------------------------------------------------
__global__ void setup_consts_kernel(const float* __restrict__ intr,
                                    float* __restrict__ C) {
  int b = threadIdx.x;
  if (b >= 2) return;
  float A[4][4], inv[4][4];
  for (int r = 0; r < 4; ++r)
    for (int c = 0; c < 4; ++c) {
      A[r][c] = intr[b * 16 + r * 4 + c];
      inv[r][c] = (r == c) ? 1.f : 0.f;
    }
  for (int k = 0; k < 4; ++k) {
    int piv = k; float best = fabsf(A[k][k]);
    for (int r = k + 1; r < 4; ++r) {
      float v = fabsf(A[r][k]);
      if (v > best) { best = v; piv = r; }
    }
    if (piv != k) {
      for (int c = 0; c < 4; ++c) {
        float t = A[k][c]; A[k][c] = A[piv][c]; A[piv][c] = t;
        t = inv[k][c]; inv[k][c] = inv[piv][c]; inv[piv][c] = t;
      }
    }
    float ip = 1.f / A[k][k];
    for (int c = 0; c < 4; ++c) { A[k][c] *= ip; inv[k][c] *= ip; }
    for (int r = 0; r < 4; ++r) if (r != k) {
      float f = A[r][k];
      for (int c = 0; c < 4; ++c) { A[r][c] -= f * A[k][c]; inv[r][c] -= f * inv[k][c]; }
    }
  }
  const float cpx[4][2] = {{0.f, 0.f}, {320.f, 0.f}, {0.f, 240.f}, {320.f, 240.f}};
  float fmn[3] = {1e30f, 1e30f, 1e30f}, fmx[3] = {-1e30f, -1e30f, -1e30f};
  for (int zi = 0; zi < 2; ++zi) {
    float z = zi ? 6.0f : 0.4f;
    for (int i = 0; i < 4; ++i) {
      float px = cpx[i][0] * z, py = cpx[i][1] * z;
      for (int ax = 0; ax < 3; ++ax) {
        float v = inv[ax][0] * px + inv[ax][1] * py + inv[ax][2] * z + inv[ax][3];
        fmn[ax] = fminf(fmn[ax], v);
        fmx[ax] = fmaxf(fmx[ax], v);
      }
    }
  }
  float* Cb = C + b * 32;
  for (int r = 0; r < 4; ++r)
    for (int c = 0; c < 4; ++c) Cb[r * 4 + c] = inv[r][c];
  for (int ax = 0; ax < 3; ++ax) {
    Cb[16 + ax] = -fmn[ax] / 0.03f;
    Cb[19 + ax] = (256.0f - (fmx[ax] - fmn[ax]) / 0.03f) * 0.5f;
  }
}

// ---------------------------------------------------------------------------
// Main kernel, 256 threads / 64 pixels.
// Phase 0 (3-way parallel): grp0 projection+mask+frac/fcz, grp1 enc taps,
//                           grp2 seg taps.
// Phase 1: tpl[p][2+ch] = bilinear * m  (lanes=pixels -> coalesced gathers)
// Phase 2: iterate TEMPLATE float2s; each lane stores its float2 to all 7
//          replicas via imm-offset stores (0,360,...,2160B). No decode math.
// ---------------------------------------------------------------------------
__global__ __launch_bounds__(256) void sparse_proj_kernel(
    const float* __restrict__ depth, const float* __restrict__ enc,
    const float* __restrict__ seg, const float* __restrict__ C,
    float* __restrict__ out) {
  __shared__ float tpl[BPIX * TPLS];   // idx 2..86 samp, 87 fc_x, 88 fc_y
  __shared__ float mArr[BPIX], frArr[BPIX], fzArr[BPIX];
  __shared__ int   eo0[BPIX], eo1[BPIX], eo2[BPIX], eo3[BPIX];
  __shared__ float ew0[BPIX], ew1[BPIX], ew2[BPIX], ew3[BPIX];
  __shared__ int   so0[BPIX], so1[BPIX], so2[BPIX], so3[BPIX];
  __shared__ float sw0[BPIX], sw1[BPIX], sw2[BPIX], sw3[BPIX];

  const int tid = threadIdx.x;
  const int bx  = blockIdx.x;
  const int b   = blockIdx.y;
  const float* Cb = C + b * 32;
  const int x0   = (bx % 5) * 64;   // all 64 pixels share one image row
  const int yrow = bx / 5;

  const int grp = tid >> 6;
  const int p   = tid & 63;

  if (grp == 0) {
    const float d = depth[(size_t)b * HW + bx * BPIX + p];
    const bool val = (d >= 0.4f) && (d <= 6.0f);
    const float m = val ? 1.f : 0.f;
    const float z = val ? d : 0.f;
    const float nx = (float)(x0 + p) / 320.f;
    const float ny = (float)yrow / 240.f;
    const float xv = nx * 320.f * z;   // replicate reference rounding path
    const float yv = ny * 240.f * z;
    const float q0 = Cb[0] * xv + Cb[1] * yv + Cb[2] * z + Cb[3];
    const float q1 = Cb[4] * xv + Cb[5] * yv + Cb[6] * z + Cb[7];
    const float q2 = Cb[8] * xv + Cb[9] * yv + Cb[10] * z + Cb[11];
    const float q3 = Cb[12] * xv + Cb[13] * yv + Cb[14] * z + Cb[15];
    const float INV_V = (float)(1.0 / 0.03);
    const float gcx = q0 * INV_V + Cb[16] * q3;
    const float gcy = q1 * INV_V + Cb[17] * q3;
    const float gcz = q2 * INV_V + Cb[18] * q3;
    mArr[p]  = m;
    frArr[p] = gcz - truncf(gcz);
    fzArr[p] = (gcz + Cb[21]) * m;
    tpl[p * TPLS + 87] = (gcx + Cb[19]) * m;
    tpl[p * TPLS + 88] = (gcy + Cb[20]) * m;
  } else if (grp == 1) {
    const float nx = (float)(x0 + p) / 320.f;
    const float ny = (float)yrow / 240.f;
    const float ix = nx * 160.f - 0.5f;
    const float iy = ny * 120.f - 0.5f;
    const float x0f = floorf(ix), y0f = floorf(iy);
    const float wx = ix - x0f, wy = iy - y0f;
    const int xi0 = (int)x0f, yi0 = (int)y0f;
    const int xi1 = xi0 + 1, yi1 = yi0 + 1;
    const float vx0 = (xi0 >= 0 && xi0 < ENC_W) ? 1.f : 0.f;
    const float vx1 = (xi1 >= 0 && xi1 < ENC_W) ? 1.f : 0.f;
    const float vy0 = (yi0 >= 0 && yi0 < ENC_H) ? 1.f : 0.f;
    const float vy1 = (yi1 >= 0 && yi1 < ENC_H) ? 1.f : 0.f;
    const int xc0 = min(max(xi0, 0), ENC_W - 1), xc1 = min(max(xi1, 0), ENC_W - 1);
    const int yc0 = min(max(yi0, 0), ENC_H - 1), yc1 = min(max(yi1, 0), ENC_H - 1);
    eo0[p] = yc0 * ENC_W + xc0; ew0[p] = (1.f - wx) * (1.f - wy) * vx0 * vy0;
    eo1[p] = yc0 * ENC_W + xc1; ew1[p] = wx * (1.f - wy) * vx1 * vy0;
    eo2[p] = yc1 * ENC_W + xc0; ew2[p] = (1.f - wx) * wy * vx0 * vy1;
    eo3[p] = yc1 * ENC_W + xc1; ew3[p] = wx * wy * vx1 * vy1;
  } else if (grp == 2) {
    const float nx = (float)(x0 + p) / 320.f;
    const float ny = (float)yrow / 240.f;
    const float ix = nx * 320.f - 0.5f;
    const float iy = ny * 240.f - 0.5f;
    const float x0f = floorf(ix), y0f = floorf(iy);
    const float wx = ix - x0f, wy = iy - y0f;
    const int xi0 = (int)x0f, yi0 = (int)y0f;
    const int xi1 = xi0 + 1, yi1 = yi0 + 1;
    const float vx0 = (xi0 >= 0 && xi0 < W_) ? 1.f : 0.f;
    const float vx1 = (xi1 >= 0 && xi1 < W_) ? 1.f : 0.f;
    const float vy0 = (yi0 >= 0 && yi0 < H_) ? 1.f : 0.f;
    const float vy1 = (yi1 >= 0 && yi1 < H_) ? 1.f : 0.f;
    const int xc0 = min(max(xi0, 0), W_ - 1), xc1 = min(max(xi1, 0), W_ - 1);
    const int yc0 = min(max(yi0, 0), H_ - 1), yc1 = min(max(yi1, 0), H_ - 1);
    so0[p] = yc0 * W_ + xc0; sw0[p] = (1.f - wx) * (1.f - wy) * vx0 * vy0;
    so1[p] = yc0 * W_ + xc1; sw1[p] = wx * (1.f - wy) * vx1 * vy0;
    so2[p] = yc1 * W_ + xc0; sw2[p] = (1.f - wx) * wy * vx0 * vy1;
    so3[p] = yc1 * W_ + xc1; sw3[p] = wx * wy * vx1 * vy1;
  }
  __syncthreads();

  // Phase 1: lanes = pixels (coalesced taps), loop over 85 channels
  for (int idx = tid; idx < BPIX * NCH; idx += 256) {
    const int pp = idx & (BPIX - 1);
    const int ch = idx >> 6;   // wave-uniform
    float v;
    if (ch < CENC) {
      const float* fb = enc + ((size_t)b * CENC + ch) * (ENC_H * ENC_W);
      v = ew0[pp] * fb[eo0[pp]] + ew1[pp] * fb[eo1[pp]] +
          ew2[pp] * fb[eo2[pp]] + ew3[pp] * fb[eo3[pp]];
    } else {
      const float* fb = seg + ((size_t)b * CSEG + (ch - CENC)) * (size_t)HW;
      v = sw0[pp] * fb[so0[pp]] + sw1[pp] * fb[so1[pp]] +
          sw2[pp] * fb[so2[pp]] + sw3[pp] * fb[so3[pp]];
    }
    tpl[pp * TPLS + 2 + ch] = v * mArr[pp];
  }
  __syncthreads();

  // Phase 2: template-major replication.
  // t -> (pixel pq = t/45, float2 col c2 = t%45). Output floats [2c2, 2c2+1].
  //  c2==0      : (sign, abs)           -- r-dependent, computed inline
  //  c2 in 1..43: tpl[2c2], tpl[2c2+1]  -- identical across the 7 reps
  //  c2==44     : (fc_y, fc_z + (r-3)m) -- .y r-dependent
  // 7 stores per lane with immediate byte offsets 0,360,...,2160.
  float* const base_out = out + (size_t)(b * HW + bx * BPIX) * PIXF;
  for (int t = tid; t < NT2; t += 256) {
    const int pq = t / 45;              // compiler magic-mul
    const int c2 = t - pq * 45;
    float2* dst = reinterpret_cast<float2*>(base_out + pq * PIXF + c2 * 2);
    if (c2 == 0) {
      const float m = mArr[pq], fr = frArr[pq];
#pragma unroll
      for (int r = 0; r < 7; ++r) {
        const float df = fr + (float)(r - 3);
        const float s = (df > 0.f) ? 1.f : ((df < 0.f) ? -1.f : 0.f);
        dst[r * 45] = make_float2(s * m, fabsf(df) * m);
      }
    } else if (c2 == 44) {
      const float m = mArr[pq];
      const float fy = tpl[pq * TPLS + 88];
      const float fz = fzArr[pq];
#pragma unroll
      for (int r = 0; r < 7; ++r)
        dst[r * 45] = make_float2(fy, fz + (float)(r - 3) * m);
    } else {
      const float2 v = *reinterpret_cast<const float2*>(&tpl[pq * TPLS + 2 * c2]);
#pragma unroll
      for (int r = 0; r < 7; ++r)
        dst[r * 45] = v;                // imm-offset stores, same data
    }
  }
}

extern "C" void kernel_launch(void* const* d_in, const int* in_sizes, int n_in,
                              void* d_out, int out_size, void* d_ws, size_t ws_size,
                              hipStream_t stream) {
  const float* depth = (const float*)d_in[0];
  const float* enc   = (const float*)d_in[1];
  const float* seg   = (const float*)d_in[2];
  const float* intr  = (const float*)d_in[3];
  float* out = (float*)d_out;
  float* C   = (float*)d_ws;   // 2 * 32 floats

  setup_consts_kernel<<<1, 64, 0, stream>>>(intr, C);
  dim3 grid(HW / BPIX, 2);
  sparse_proj_kernel<<<grid, 256, 0, stream>>>(depth, enc, seg, C, out);
}

// Round 7
// 455.875 us; speedup vs baseline: 1.0377x; 1.0377x over previous
//
#include <hip/hip_runtime.h>
#include <math.h>

#define BPIX 64      // pixels per block (one row segment: 320 = 5*64)
#define HW   76800   // H*W
#define W_   320
#define H_   240
#define ENC_W 160
#define ENC_H 120
#define CENC 64
#define CSEG 21
#define NCH  85      // CENC + CSEG
#define ROW  90      // floats per output row
#define PIXF 630     // 7 * 90 floats per pixel
#define TPLS 94      // template row stride (even -> float2 aligned)
#define NT2  2880    // BPIX * 45 template float2 positions per block

// ---------------------------------------------------------------------------
// Per-batch constants: K_inv (16), c2f translation -fmin/VOXEL (3), pad_off (3)
// ---------------------------------------------------------------------------
__global__ void setup_consts_kernel(const float* __restrict__ intr,
                                    float* __restrict__ C) {
  int b = threadIdx.x;
  if (b >= 2) return;
  float A[4][4], inv[4][4];
  for (int r = 0; r < 4; ++r)
    for (int c = 0; c < 4; ++c) {
      A[r][c] = intr[b * 16 + r * 4 + c];
      inv[r][c] = (r == c) ? 1.f : 0.f;
    }
  for (int k = 0; k < 4; ++k) {
    int piv = k; float best = fabsf(A[k][k]);
    for (int r = k + 1; r < 4; ++r) {
      float v = fabsf(A[r][k]);
      if (v > best) { best = v; piv = r; }
    }
    if (piv != k) {
      for (int c = 0; c < 4; ++c) {
        float t = A[k][c]; A[k][c] = A[piv][c]; A[piv][c] = t;
        t = inv[k][c]; inv[k][c] = inv[piv][c]; inv[piv][c] = t;
      }
    }
    float ip = 1.f / A[k][k];
    for (int c = 0; c < 4; ++c) { A[k][c] *= ip; inv[k][c] *= ip; }
    for (int r = 0; r < 4; ++r) if (r != k) {
      float f = A[r][k];
      for (int c = 0; c < 4; ++c) { A[r][c] -= f * A[k][c]; inv[r][c] -= f * inv[k][c]; }
    }
  }
  const float cpx[4][2] = {{0.f, 0.f}, {320.f, 0.f}, {0.f, 240.f}, {320.f, 240.f}};
  float fmn[3] = {1e30f, 1e30f, 1e30f}, fmx[3] = {-1e30f, -1e30f, -1e30f};
  for (int zi = 0; zi < 2; ++zi) {
    float z = zi ? 6.0f : 0.4f;
    for (int i = 0; i < 4; ++i) {
      float px = cpx[i][0] * z, py = cpx[i][1] * z;
      for (int ax = 0; ax < 3; ++ax) {
        float v = inv[ax][0] * px + inv[ax][1] * py + inv[ax][2] * z + inv[ax][3];
        fmn[ax] = fminf(fmn[ax], v);
        fmx[ax] = fmaxf(fmx[ax], v);
      }
    }
  }
  float* Cb = C + b * 32;
  for (int r = 0; r < 4; ++r)
    for (int c = 0; c < 4; ++c) Cb[r * 4 + c] = inv[r][c];
  for (int ax = 0; ax < 3; ++ax) {
    Cb[16 + ax] = -fmn[ax] / 0.03f;
    Cb[19 + ax] = (256.0f - (fmx[ax] - fmn[ax]) / 0.03f) * 0.5f;
  }
}

// ---------------------------------------------------------------------------
// Main kernel, 256 threads / 64 pixels. Single barrier.
// Every wave: projection + tap offsets/weights in REGISTERS for its 64 lanes
//             (no tap LDS, no phase-0 barrier). Wave 0 stores the 5 per-pixel
//             scalars phase 2 needs.
// Phase 1: tpl[p][2+ch] = bilinear * m  (lanes=pixels, reg addresses/weights)
// Phase 2: template-major replication, 7 imm-offset float2 stores per elem,
//          carried (pq,c2) counters (no div/mod).
// ---------------------------------------------------------------------------
__global__ __launch_bounds__(256) void sparse_proj_kernel(
    const float* __restrict__ depth, const float* __restrict__ enc,
    const float* __restrict__ seg, const float* __restrict__ C,
    float* __restrict__ out) {
  __shared__ float tpl[BPIX * TPLS];   // idx 2..86 samp, 87 fc_x, 88 fc_y
  __shared__ float mArr[BPIX], frArr[BPIX], fzArr[BPIX];

  const int tid = threadIdx.x;
  const int bx  = blockIdx.x;
  const int b   = blockIdx.y;
  const float* Cb = C + b * 32;
  const int x0   = (bx % 5) * 64;   // all 64 pixels share one image row
  const int yrow = bx / 5;
  const int p    = tid & 63;        // lane = pixel

  // ---- per-wave register setup (redundant across waves; no barrier needed)
  const float d = depth[(size_t)b * HW + bx * BPIX + p];
  const bool val = (d >= 0.4f) && (d <= 6.0f);
  const float m = val ? 1.f : 0.f;
  const float z = val ? d : 0.f;
  const float nx = (float)(x0 + p) / 320.f;
  const float ny = (float)yrow / 240.f;

  if (tid < 64) {  // wave 0: projection + per-pixel scalars for phase 2
    const float xv = nx * 320.f * z;   // replicate reference rounding path
    const float yv = ny * 240.f * z;
    const float q0 = Cb[0] * xv + Cb[1] * yv + Cb[2] * z + Cb[3];
    const float q1 = Cb[4] * xv + Cb[5] * yv + Cb[6] * z + Cb[7];
    const float q2 = Cb[8] * xv + Cb[9] * yv + Cb[10] * z + Cb[11];
    const float q3 = Cb[12] * xv + Cb[13] * yv + Cb[14] * z + Cb[15];
    const float INV_V = (float)(1.0 / 0.03);
    const float gcx = q0 * INV_V + Cb[16] * q3;
    const float gcy = q1 * INV_V + Cb[17] * q3;
    const float gcz = q2 * INV_V + Cb[18] * q3;
    mArr[p]  = m;
    frArr[p] = gcz - truncf(gcz);
    fzArr[p] = (gcz + Cb[21]) * m;
    tpl[p * TPLS + 87] = (gcx + Cb[19]) * m;
    tpl[p * TPLS + 88] = (gcy + Cb[20]) * m;
  }

  // encoder taps (registers)
  int eo0, eo1, eo2, eo3; float ew0, ew1, ew2, ew3;
  {
    const float ix = nx * 160.f - 0.5f;
    const float iy = ny * 120.f - 0.5f;
    const float x0f = floorf(ix), y0f = floorf(iy);
    const float wx = ix - x0f, wy = iy - y0f;
    const int xi0 = (int)x0f, yi0 = (int)y0f;
    const int xi1 = xi0 + 1, yi1 = yi0 + 1;
    const float vx0 = (xi0 >= 0 && xi0 < ENC_W) ? 1.f : 0.f;
    const float vx1 = (xi1 >= 0 && xi1 < ENC_W) ? 1.f : 0.f;
    const float vy0 = (yi0 >= 0 && yi0 < ENC_H) ? 1.f : 0.f;
    const float vy1 = (yi1 >= 0 && yi1 < ENC_H) ? 1.f : 0.f;
    const int xc0 = min(max(xi0, 0), ENC_W - 1), xc1 = min(max(xi1, 0), ENC_W - 1);
    const int yc0 = min(max(yi0, 0), ENC_H - 1), yc1 = min(max(yi1, 0), ENC_H - 1);
    eo0 = yc0 * ENC_W + xc0; ew0 = (1.f - wx) * (1.f - wy) * vx0 * vy0;
    eo1 = yc0 * ENC_W + xc1; ew1 = wx * (1.f - wy) * vx1 * vy0;
    eo2 = yc1 * ENC_W + xc0; ew2 = (1.f - wx) * wy * vx0 * vy1;
    eo3 = yc1 * ENC_W + xc1; ew3 = wx * wy * vx1 * vy1;
  }
  // seg taps (registers)
  int so0, so1, so2, so3; float sw0, sw1, sw2, sw3;
  {
    const float ix = nx * 320.f - 0.5f;
    const float iy = ny * 240.f - 0.5f;
    const float x0f = floorf(ix), y0f = floorf(iy);
    const float wx = ix - x0f, wy = iy - y0f;
    const int xi0 = (int)x0f, yi0 = (int)y0f;
    const int xi1 = xi0 + 1, yi1 = yi0 + 1;
    const float vx0 = (xi0 >= 0 && xi0 < W_) ? 1.f : 0.f;
    const float vx1 = (xi1 >= 0 && xi1 < W_) ? 1.f : 0.f;
    const float vy0 = (yi0 >= 0 && yi0 < H_) ? 1.f : 0.f;
    const float vy1 = (yi1 >= 0 && yi1 < H_) ? 1.f : 0.f;
    const int xc0 = min(max(xi0, 0), W_ - 1), xc1 = min(max(xi1, 0), W_ - 1);
    const int yc0 = min(max(yi0, 0), H_ - 1), yc1 = min(max(yi1, 0), H_ - 1);
    so0 = yc0 * W_ + xc0; sw0 = (1.f - wx) * (1.f - wy) * vx0 * vy0;
    so1 = yc0 * W_ + xc1; sw1 = wx * (1.f - wy) * vx1 * vy0;
    so2 = yc1 * W_ + xc0; sw2 = (1.f - wx) * wy * vx0 * vy1;
    so3 = yc1 * W_ + xc1; sw3 = wx * wy * vx1 * vy1;
  }

  // Phase 1: ch = (tid>>6) + 4k (wave-uniform), addresses/weights in regs
  for (int idx = tid; idx < BPIX * NCH; idx += 256) {
    const int ch = idx >> 6;
    float v;
    if (ch < CENC) {
      const float* fb = enc + ((size_t)b * CENC + ch) * (ENC_H * ENC_W);
      v = ew0 * fb[eo0] + ew1 * fb[eo1] + ew2 * fb[eo2] + ew3 * fb[eo3];
    } else {
      const float* fb = seg + ((size_t)b * CSEG + (ch - CENC)) * (size_t)HW;
      v = sw0 * fb[so0] + sw1 * fb[so1] + sw2 * fb[so2] + sw3 * fb[so3];
    }
    tpl[p * TPLS + 2 + ch] = v * m;
  }
  __syncthreads();

  // Phase 2: template-major replication with carried (pq, c2) counters.
  //  c2==0      : (sign, abs)            r-dependent
  //  c2 in 1..43: tpl[2c2], tpl[2c2+1]   identical across reps
  //  c2==44     : (fc_y, fc_z + (r-3)m)  .y r-dependent
  float* const base_out = out + (size_t)(b * HW + bx * BPIX) * PIXF;
  {
    int pq = tid / 45;           // once
    int c2 = tid - pq * 45;
    for (int t = tid; t < NT2; t += 256) {
      float2* dst = reinterpret_cast<float2*>(base_out + pq * PIXF + c2 * 2);
      if (c2 == 0) {
        const float mm = mArr[pq], fr = frArr[pq];
#pragma unroll
        for (int r = 0; r < 7; ++r) {
          const float df = fr + (float)(r - 3);
          const float s = (df > 0.f) ? 1.f : ((df < 0.f) ? -1.f : 0.f);
          dst[r * 45] = make_float2(s * mm, fabsf(df) * mm);
        }
      } else if (c2 == 44) {
        const float mm = mArr[pq];
        const float fy = tpl[pq * TPLS + 88];
        const float fz = fzArr[pq];
#pragma unroll
        for (int r = 0; r < 7; ++r)
          dst[r * 45] = make_float2(fy, fz + (float)(r - 3) * mm);
      } else {
        const float2 v = *reinterpret_cast<const float2*>(&tpl[pq * TPLS + 2 * c2]);
#pragma unroll
        for (int r = 0; r < 7; ++r)
          dst[r * 45] = v;
      }
      // advance by 256 template slots: 256 = 5*45 + 31
      c2 += 31; pq += 5;
      if (c2 >= 45) { c2 -= 45; ++pq; }
    }
  }
}

extern "C" void kernel_launch(void* const* d_in, const int* in_sizes, int n_in,
                              void* d_out, int out_size, void* d_ws, size_t ws_size,
                              hipStream_t stream) {
  const float* depth = (const float*)d_in[0];
  const float* enc   = (const float*)d_in[1];
  const float* seg   = (const float*)d_in[2];
  const float* intr  = (const float*)d_in[3];
  float* out = (float*)d_out;
  float* C   = (float*)d_ws;   // 2 * 32 floats

  setup_consts_kernel<<<1, 64, 0, stream>>>(intr, C);
  dim3 grid(HW / BPIX, 2);
  sparse_proj_kernel<<<grid, 256, 0, stream>>>(depth, enc, seg, C, out);
}